// Round 3
// baseline (333.682 us; speedup 1.0000x reference)
//
#include <hip/hip_runtime.h>

// Problem constants: B=4, C=64, H=W=64, N=4096
// Workspace layout (float offsets) — 4,747,264 floats (same proven footprint).
#define OFF_POS   0u
#define OFF_QTH   1048576u
#define OFF_QTL   1572864u
#define OFF_KTH   2097152u
#define OFF_KTL   2621440u
#define OFF_VBH   3145728u
#define OFF_VBL   3670016u
#define OFF_WT    4194304u
#define OFF_LPART 4304896u                 // 8 * 4 * 4096 = 131072
#define OFF_INVL  4452352u
#define OFF_GPART 4468736u
#define OFF_A     4730880u
#define WS_FLOATS 4747264u

typedef short s8v __attribute__((ext_vector_type(8)));
typedef float f4v __attribute__((ext_vector_type(4)));

#define MFMA16(a, b, c) __builtin_amdgcn_mfma_f32_16x16x32_bf16((a), (b), (c), 0, 0, 0)

__device__ __forceinline__ unsigned short bf16_rne(float f) {
    union { float f; unsigned int u; } v; v.f = f;
    unsigned int r = v.u + 0x7FFFu + ((v.u >> 16) & 1u);
    return (unsigned short)(r >> 16);
}
__device__ __forceinline__ void split2(float f, unsigned short& h, unsigned short& l) {
    unsigned short hh = bf16_rne(f);
    union { unsigned int u; float f; } b; b.u = ((unsigned int)hh) << 16;
    h = hh;
    l = bf16_rne(f - b.f);
}

// ---------------- weight transpose: w[o][ci][3][3] -> wt[conv][ci*9+tap][o]
__global__ void k_wtrans(const float* __restrict__ wq, const float* __restrict__ wk,
                         const float* __restrict__ wv, float* __restrict__ wt) {
    int idx = blockIdx.x * 256 + threadIdx.x;     // < 3*36864
    int conv = idx / 36864;
    int r = idx % 36864;
    int o = r & 63;
    int t2 = r >> 6;            // ci*9+tap
    int ci = t2 / 9, tap = t2 % 9;
    const float* w = (conv == 0) ? wq : (conv == 1) ? wk : wv;
    wt[idx] = w[(o * 64 + ci) * 9 + tap];
}

// ---------------- fused 3x3 conv (SAME) writing split-bf16 outputs:
//   q,k -> transposed [b][n][c] hi/lo arrays (for MFMA A/B fragment loads)
//   v   -> blocked [b][cb][n8][cc][e] hi/lo (c=cb*16+cc, n=n8*8+e)
__global__ __launch_bounds__(256) void k_conv(
        const float* __restrict__ x, const float* __restrict__ wt,
        const float* __restrict__ bq, const float* __restrict__ bk, const float* __restrict__ bv,
        unsigned short* __restrict__ qth, unsigned short* __restrict__ qtl,
        unsigned short* __restrict__ kth, unsigned short* __restrict__ ktl,
        unsigned short* __restrict__ vbh, unsigned short* __restrict__ vbl) {
    int h = blockIdx.x, b = blockIdx.y, conv = blockIdx.z;
    const float* bias = (conv == 0) ? bq : (conv == 1) ? bk : bv;
    const float* wtc = wt + conv * 36864;

    __shared__ float xch[16 * 3 * 66];   // [cil][dy][col], col 0 & 65 zero pad
    __shared__ float wch[16 * 9 * 64];   // [cil][tap][o]

    int tid = threadIdx.x;
    int wtd = tid & 15, ot = tid >> 4;
    int w0 = wtd * 4, o0 = ot * 4;

    float acc[4][4];
    {
        float4 b4 = *(const float4*)(bias + o0);
        float bb[4] = {b4.x, b4.y, b4.z, b4.w};
#pragma unroll
        for (int oo = 0; oo < 4; ++oo)
#pragma unroll
            for (int ww = 0; ww < 4; ++ww) acc[oo][ww] = bb[oo];
    }

    for (int ck = 0; ck < 4; ++ck) {
        __syncthreads();
        for (int idx = tid; idx < 3168; idx += 256) {
            int col = idx % 66;
            int row = idx / 66;
            int dy = row % 3, cil = row / 3;
            int ci = ck * 16 + cil;
            int hs = h + dy - 1;
            float val = 0.0f;
            if (col >= 1 && col <= 64 && hs >= 0 && hs < 64)
                val = x[((b * 64 + ci) * 64 + hs) * 64 + (col - 1)];
            xch[(cil * 3 + dy) * 66 + col] = val;
        }
        for (int idx = tid; idx < 2304; idx += 256)
            ((float4*)wch)[idx] = ((const float4*)(wtc + ck * 9216))[idx];
        __syncthreads();

        for (int cil = 0; cil < 16; ++cil) {
#pragma unroll
            for (int dy = 0; dy < 3; ++dy) {
                float xv[6];
#pragma unroll
                for (int s = 0; s < 6; ++s) xv[s] = xch[(cil * 3 + dy) * 66 + w0 + s];
#pragma unroll
                for (int dx = 0; dx < 3; ++dx) {
                    float4 w4 = ((const float4*)wch)[(cil * 9 + dy * 3 + dx) * 16 + ot];
                    float wa[4] = {w4.x, w4.y, w4.z, w4.w};
#pragma unroll
                    for (int oo = 0; oo < 4; ++oo)
#pragma unroll
                        for (int ww = 0; ww < 4; ++ww)
                            acc[oo][ww] += xv[ww + dx] * wa[oo];
                }
            }
        }
    }

    if (conv < 2) {
        unsigned short* oh = (conv == 0) ? qth : kth;
        unsigned short* ol = (conv == 0) ? qtl : ktl;
#pragma unroll
        for (int ww = 0; ww < 4; ++ww) {
            unsigned short h4[4], l4[4];
#pragma unroll
            for (int oo = 0; oo < 4; ++oo) split2(acc[oo][ww], h4[oo], l4[oo]);
            int ad = (b * 4096 + h * 64 + w0 + ww) * 64 + o0;
            uint2 hv, lv;
            hv.x = h4[0] | ((unsigned int)h4[1] << 16);
            hv.y = h4[2] | ((unsigned int)h4[3] << 16);
            lv.x = l4[0] | ((unsigned int)l4[1] << 16);
            lv.y = l4[2] | ((unsigned int)l4[3] << 16);
            *(uint2*)(oh + ad) = hv;
            *(uint2*)(ol + ad) = lv;
        }
    } else {
        int cb = o0 >> 4, ccb = o0 & 15;
#pragma unroll
        for (int ww = 0; ww < 4; ++ww) {
            int n = h * 64 + w0 + ww;
            int n8 = n >> 3, e = n & 7;
            int basead = ((b * 4 + cb) * 512 + n8) * 16;
#pragma unroll
            for (int oo = 0; oo < 4; ++oo) {
                unsigned short hh, ll;
                split2(acc[oo][ww], hh, ll);
                vbh[(basead + ccb + oo) * 8 + e] = hh;
                vbl[(basead + ccb + oo) * 8 + e] = ll;
            }
        }
    }
}

// ---------------- channel Gram partials (unchanged)
__global__ __launch_bounds__(256) void k_gram(const float* __restrict__ x, float* __restrict__ Gpart) {
    int nc = blockIdx.x, b = blockIdx.y;
    __shared__ float xs[64 * 257];
    int tid = threadIdx.x;
    for (int it = 0; it < 16; ++it) {
        int f4i = tid + it * 256;
        int c = f4i >> 6, n4 = f4i & 63;
        float4 vv = *(const float4*)(x + (b * 64 + c) * 4096 + nc * 256 + n4 * 4);
        xs[c * 257 + n4 * 4 + 0] = vv.x;
        xs[c * 257 + n4 * 4 + 1] = vv.y;
        xs[c * 257 + n4 * 4 + 2] = vv.z;
        xs[c * 257 + n4 * 4 + 3] = vv.w;
    }
    __syncthreads();
    int tc = tid & 15, td = tid >> 4;
    int c0 = tc * 4, d0 = td * 4;
    float acc[4][4];
#pragma unroll
    for (int i = 0; i < 4; ++i)
#pragma unroll
        for (int j = 0; j < 4; ++j) acc[i][j] = 0.0f;
    for (int n = 0; n < 256; ++n) {
        float xc[4], xd[4];
#pragma unroll
        for (int i = 0; i < 4; ++i) xc[i] = xs[(c0 + i) * 257 + n];
#pragma unroll
        for (int j = 0; j < 4; ++j) xd[j] = xs[(d0 + j) * 257 + n];
#pragma unroll
        for (int i = 0; i < 4; ++i)
#pragma unroll
            for (int j = 0; j < 4; ++j) acc[i][j] += xc[i] * xd[j];
    }
#pragma unroll
    for (int i = 0; i < 4; ++i) {
        float4 o4 = {acc[i][0], acc[i][1], acc[i][2], acc[i][3]};
        *(float4*)(Gpart + ((nc * 4 + b) * 64 + c0 + i) * 64 + d0) = o4;
    }
}

// ---------------- channel softmax rows (unchanged)
__global__ void k_asm(const float* __restrict__ Gpart, float* __restrict__ A) {
    int row = blockIdx.x;      // b*64 + c
    int d = threadIdx.x;
    int b = row >> 6, c = row & 63;
    float g = 0.0f;
    for (int p = 0; p < 16; ++p) g += Gpart[(p * 4 + b) * 4096 + c * 64 + d];
    float mx = g;
    for (int off = 32; off >= 1; off >>= 1) mx = fmaxf(mx, __shfl_xor(mx, off, 64));
    float e = __expf(g - mx);
    float s = e;
    for (int off = 32; off >= 1; off >>= 1) s += __shfl_xor(s, off, 64);
    A[row * 64 + d] = e / s;
}

// ---------------- pass1: row sums l_i = sum_j exp(s_ij), no max shift.
// grid 2048 = (64 itile x 4 b x 8 jp); block 256 (4 waves), wave = 16-row strip.
// Per-lane accumulation; single deferred cross-lane reduce at the end.
__global__ __launch_bounds__(256, 8) void k_pass1(
        const unsigned short* __restrict__ qth, const unsigned short* __restrict__ qtl,
        const unsigned short* __restrict__ kth, const unsigned short* __restrict__ ktl,
        float* __restrict__ lpart) {
    int flat = blockIdx.x;                 // 0..2047
    int xcd = flat & 7, hi = flat >> 3;    // hi 0..255
    int b = xcd >> 1;
    int rem = (xcd & 1) * 256 + hi;        // 0..511
    int itile = rem & 63, jp = rem >> 6;   // jp 0..7

    int tid = threadIdx.x;
    int lane = tid & 63, wv = tid >> 6;
    int l15 = lane & 15, g = lane >> 4;
    int i0 = itile * 64 + wv * 16;

    int qb = (b * 4096 + i0 + l15) * 64 + g * 8;
    s8v qa00 = *(const s8v*)(qth + qb);
    s8v qa01 = *(const s8v*)(qtl + qb);
    s8v qa10 = *(const s8v*)(qth + qb + 32);
    s8v qa11 = *(const s8v*)(qtl + qb + 32);

    float l[4] = {0.f, 0.f, 0.f, 0.f};

    for (int jt = 0; jt < 8; ++jt) {
        int j0 = jp * 512 + jt * 64;
#pragma unroll
        for (int js = 0; js < 4; ++js) {
            int kb = (b * 4096 + j0 + js * 16 + l15) * 64 + g * 8;
            s8v bh0 = *(const s8v*)(kth + kb);
            s8v bl0 = *(const s8v*)(ktl + kb);
            s8v bh1 = *(const s8v*)(kth + kb + 32);
            s8v bl1 = *(const s8v*)(ktl + kb + 32);
            f4v acc = {0.f, 0.f, 0.f, 0.f};
            acc = MFMA16(qa00, bh0, acc);
            acc = MFMA16(qa00, bl0, acc);
            acc = MFMA16(qa01, bh0, acc);
            acc = MFMA16(qa10, bh1, acc);
            acc = MFMA16(qa10, bl1, acc);
            acc = MFMA16(qa11, bh1, acc);
            l[0] += __expf(acc[0]);
            l[1] += __expf(acc[1]);
            l[2] += __expf(acc[2]);
            l[3] += __expf(acc[3]);
        }
    }
#pragma unroll
    for (int r = 0; r < 4; ++r) {
        float s = l[r];
        s += __shfl_xor(s, 1);
        s += __shfl_xor(s, 2);
        s += __shfl_xor(s, 4);
        s += __shfl_xor(s, 8);
        l[r] = s;
    }
    if (l15 == 0) {
        int ib = (jp * 4 + b) * 4096 + i0 + g * 4;
#pragma unroll
        for (int r = 0; r < 4; ++r) lpart[ib + r] = l[r];
    }
}

// ---------------- merge 8 j-partials -> 1/l
__global__ void k_merge(const float* __restrict__ lpart, float* __restrict__ invl) {
    int idx = blockIdx.x * 256 + threadIdx.x;
    float s = 0.0f;
#pragma unroll
    for (int p = 0; p < 8; ++p) s += lpart[p * 16384 + idx];
    invl[idx] = 1.0f / s;
}

// ---------------- pass2: flash pass, grid 512, block 512 (8 waves).
// Block owns (b, 32-col j-tile); loops i in steps of 128.
// QK: wave = 16-row i-strip (K frags in registers). P hi/lo staged in LDS.
// PV: wave = (c-quarter 16) x (j-half 16).
__global__ __launch_bounds__(512, 4) void k_pass2(
        const unsigned short* __restrict__ qth, const unsigned short* __restrict__ qtl,
        const unsigned short* __restrict__ kth, const unsigned short* __restrict__ ktl,
        const unsigned short* __restrict__ vbh, const unsigned short* __restrict__ vbl,
        const float* __restrict__ invl, float* __restrict__ pos) {
    int flat = blockIdx.x;                      // 0..511
    int xcd = flat & 7;
    int b = xcd >> 1;
    int jt = (xcd & 1) * 64 + (flat >> 3);      // 0..127
    int j0 = jt * 32;

    int tid = threadIdx.x;
    int lane = tid & 63, wv = tid >> 6;
    int l15 = lane & 15, g = lane >> 4;

    __shared__ unsigned short Ph[32][136];
    __shared__ unsigned short Pl[32][136];

    // K fragments for 32 j, registers: [jsub][cchunk][hi/lo]
    s8v kf[2][2][2];
#pragma unroll
    for (int js = 0; js < 2; ++js) {
        int kb = (b * 4096 + j0 + js * 16 + l15) * 64 + g * 8;
        kf[js][0][0] = *(const s8v*)(kth + kb);
        kf[js][0][1] = *(const s8v*)(ktl + kb);
        kf[js][1][0] = *(const s8v*)(kth + kb + 32);
        kf[js][1][1] = *(const s8v*)(ktl + kb + 32);
    }

    int cq = wv & 3, jh = wv >> 2;
    f4v oa = {0.f, 0.f, 0.f, 0.f};

    for (int it = 0; it < 32; ++it) {
        int i0 = it * 128;
        int iw = i0 + wv * 16;
        int qb = (b * 4096 + iw + l15) * 64 + g * 8;
        s8v qa00 = *(const s8v*)(qth + qb);
        s8v qa01 = *(const s8v*)(qtl + qb);
        s8v qa10 = *(const s8v*)(qth + qb + 32);
        s8v qa11 = *(const s8v*)(qtl + qb + 32);
        float4 v4 = *(const float4*)(invl + b * 4096 + iw + g * 4);
        float ivr[4] = {v4.x, v4.y, v4.z, v4.w};

        __syncthreads();   // previous iteration's P reads complete
#pragma unroll
        for (int js = 0; js < 2; ++js) {
            f4v acc = {0.f, 0.f, 0.f, 0.f};
            acc = MFMA16(qa00, kf[js][0][0], acc);
            acc = MFMA16(qa00, kf[js][0][1], acc);
            acc = MFMA16(qa01, kf[js][0][0], acc);
            acc = MFMA16(qa10, kf[js][1][0], acc);
            acc = MFMA16(qa10, kf[js][1][1], acc);
            acc = MFMA16(qa11, kf[js][1][0], acc);
            unsigned short hh[4], ll[4];
#pragma unroll
            for (int r = 0; r < 4; ++r) {
                float w = __expf(acc[r]) * ivr[r];
                split2(w, hh[r], ll[r]);
            }
            uint2 hv, lv;
            hv.x = hh[0] | ((unsigned int)hh[1] << 16);
            hv.y = hh[2] | ((unsigned int)hh[3] << 16);
            lv.x = ll[0] | ((unsigned int)ll[1] << 16);
            lv.y = ll[2] | ((unsigned int)ll[3] << 16);
            int row = js * 16 + l15, col = wv * 16 + g * 4;
            *(uint2*)&Ph[row][col] = hv;
            *(uint2*)&Pl[row][col] = lv;
        }
        __syncthreads();   // P tile ready
#pragma unroll
        for (int ic = 0; ic < 4; ++ic) {
            int n8 = it * 16 + ic * 4 + g;
            int va = (((b * 4 + cq) * 512 + n8) * 16 + l15) * 8;
            s8v ah = *(const s8v*)(vbh + va);
            s8v al = *(const s8v*)(vbl + va);
            int ilocal = ic * 32 + g * 8;
            s8v bh = *(const s8v*)&Ph[jh * 16 + l15][ilocal];
            s8v bl = *(const s8v*)&Pl[jh * 16 + l15][ilocal];
            oa = MFMA16(ah, bh, oa);
            oa = MFMA16(ah, bl, oa);
            oa = MFMA16(al, bh, oa);
        }
    }
    int cb = b * 64 + cq * 16 + g * 4;
    int jb = j0 + jh * 16 + l15;
#pragma unroll
    for (int r = 0; r < 4; ++r)
        pos[(cb + r) * 4096 + jb] = oa[r];
}

// ---------------- final: out = pg*pos + cg*(A@x) + 2*x, LDS-staged x tile
__global__ __launch_bounds__(256) void k_final(
        const float* __restrict__ x, const float* __restrict__ pos,
        const float* __restrict__ A, const float* __restrict__ pg,
        const float* __restrict__ cg, float* __restrict__ out) {
    int n0 = blockIdx.x * 256, cg8 = blockIdx.y, b = blockIdx.z;
    __shared__ float xs[64 * 256];
    int tid = threadIdx.x;
    for (int it = 0; it < 16; ++it) {
        int idx = tid + it * 256;           // float4 index
        int d = idx >> 6, n4 = idx & 63;
        *(float4*)(xs + d * 256 + n4 * 4) =
            *(const float4*)(x + (b * 64 + d) * 4096 + n0 + n4 * 4);
    }
    __syncthreads();
    float pgv = pg[0], cgv = cg[0];
    int cbase = cg8 * 8;
#pragma unroll
    for (int c8 = 0; c8 < 8; ++c8) {
        int c = cbase + c8;
        const float* Ar = A + (b * 64 + c) * 64;
        float acc = 0.0f;
#pragma unroll
        for (int d = 0; d < 64; ++d) acc += Ar[d] * xs[d * 256 + tid];
        float xc = xs[c * 256 + tid];
        float p = pos[(b * 64 + c) * 4096 + n0 + tid];
        out[(b * 64 + c) * 4096 + n0 + tid] = pgv * p + cgv * acc + 2.0f * xc;
    }
}

extern "C" void kernel_launch(void* const* d_in, const int* in_sizes, int n_in,
                              void* d_out, int out_size, void* d_ws, size_t ws_size,
                              hipStream_t stream) {
    const float* x  = (const float*)d_in[0];
    const float* wq = (const float*)d_in[1];
    const float* bq = (const float*)d_in[2];
    const float* wk = (const float*)d_in[3];
    const float* bk = (const float*)d_in[4];
    const float* wv = (const float*)d_in[5];
    const float* bv = (const float*)d_in[6];
    const float* pg = (const float*)d_in[7];
    const float* cg = (const float*)d_in[8];
    float* out = (float*)d_out;

    if (ws_size < (size_t)WS_FLOATS * sizeof(float)) return;
    float* ws = (float*)d_ws;
    float* pos  = ws + OFF_POS;
    unsigned short* qth = (unsigned short*)(ws + OFF_QTH);
    unsigned short* qtl = (unsigned short*)(ws + OFF_QTL);
    unsigned short* kth = (unsigned short*)(ws + OFF_KTH);
    unsigned short* ktl = (unsigned short*)(ws + OFF_KTL);
    unsigned short* vbh = (unsigned short*)(ws + OFF_VBH);
    unsigned short* vbl = (unsigned short*)(ws + OFF_VBL);
    float* wt   = ws + OFF_WT;
    float* lp   = ws + OFF_LPART;
    float* invl = ws + OFF_INVL;
    float* Gp   = ws + OFF_GPART;
    float* A    = ws + OFF_A;

    k_wtrans<<<432, 256, 0, stream>>>(wq, wk, wv, wt);
    k_conv<<<dim3(64, 4, 3), 256, 0, stream>>>(x, wt, bq, bk, bv, qth, qtl, kth, ktl, vbh, vbl);
    k_gram<<<dim3(16, 4), 256, 0, stream>>>(x, Gp);
    k_asm<<<256, 64, 0, stream>>>(Gp, A);
    k_pass1<<<2048, 256, 0, stream>>>(qth, qtl, kth, ktl, lp);
    k_merge<<<64, 256, 0, stream>>>(lp, invl);
    k_pass2<<<512, 512, 0, stream>>>(qth, qtl, kth, ktl, vbh, vbl, invl, pos);
    k_final<<<dim3(16, 8, 4), 256, 0, stream>>>(x, pos, A, pg, cg, out);
}

// Round 4
// 206.522 us; speedup vs baseline: 1.6157x; 1.6157x over previous
//
#include <hip/hip_runtime.h>

// Problem constants: B=4, C=64, H=W=64, N=4096
// Workspace layout (float offsets) — 4,747,264 floats (same proven footprint).
#define OFF_POS   0u
#define OFF_QTH   1048576u
#define OFF_QTL   1572864u
#define OFF_KTH   2097152u
#define OFF_KTL   2621440u
#define OFF_VBH   3145728u
#define OFF_VBL   3670016u
#define OFF_WT    4194304u
#define OFF_LPART 4304896u                 // 8 * 4 * 4096 = 131072
#define OFF_INVL  4452352u
#define OFF_GPART 4468736u
#define OFF_A     4730880u
#define WS_FLOATS 4747264u

typedef short s8v __attribute__((ext_vector_type(8)));
typedef float f4v __attribute__((ext_vector_type(4)));

#define MFMA16(a, b, c) __builtin_amdgcn_mfma_f32_16x16x32_bf16((a), (b), (c), 0, 0, 0)

__device__ __forceinline__ unsigned short bf16_rne(float f) {
    union { float f; unsigned int u; } v; v.f = f;
    unsigned int r = v.u + 0x7FFFu + ((v.u >> 16) & 1u);
    return (unsigned short)(r >> 16);
}
__device__ __forceinline__ void split2(float f, unsigned short& h, unsigned short& l) {
    unsigned short hh = bf16_rne(f);
    union { unsigned int u; float f; } b; b.u = ((unsigned int)hh) << 16;
    h = hh;
    l = bf16_rne(f - b.f);
}
// async global->LDS: each lane copies 16B from its own global addr to ldsbase + lane*16
__device__ __forceinline__ void gl_lds16(const unsigned short* g, unsigned short* l) {
    __builtin_amdgcn_global_load_lds(
        (const __attribute__((address_space(1))) unsigned int*)g,
        (__attribute__((address_space(3))) unsigned int*)l, 16, 0, 0);
}

// ---------------- weight transpose: w[o][ci][3][3] -> wt[conv][ci*9+tap][o]
__global__ void k_wtrans(const float* __restrict__ wq, const float* __restrict__ wk,
                         const float* __restrict__ wv, float* __restrict__ wt) {
    int idx = blockIdx.x * 256 + threadIdx.x;     // < 3*36864
    int conv = idx / 36864;
    int r = idx % 36864;
    int o = r & 63;
    int t2 = r >> 6;            // ci*9+tap
    int ci = t2 / 9, tap = t2 % 9;
    const float* w = (conv == 0) ? wq : (conv == 1) ? wk : wv;
    wt[idx] = w[(o * 64 + ci) * 9 + tap];
}

// ---------------- fused 3x3 conv (SAME) writing split-bf16 outputs
__global__ __launch_bounds__(256) void k_conv(
        const float* __restrict__ x, const float* __restrict__ wt,
        const float* __restrict__ bq, const float* __restrict__ bk, const float* __restrict__ bv,
        unsigned short* __restrict__ qth, unsigned short* __restrict__ qtl,
        unsigned short* __restrict__ kth, unsigned short* __restrict__ ktl,
        unsigned short* __restrict__ vbh, unsigned short* __restrict__ vbl) {
    int h = blockIdx.x, b = blockIdx.y, conv = blockIdx.z;
    const float* bias = (conv == 0) ? bq : (conv == 1) ? bk : bv;
    const float* wtc = wt + conv * 36864;

    __shared__ float xch[16 * 3 * 66];   // [cil][dy][col], col 0 & 65 zero pad
    __shared__ float wch[16 * 9 * 64];   // [cil][tap][o]

    int tid = threadIdx.x;
    int wtd = tid & 15, ot = tid >> 4;
    int w0 = wtd * 4, o0 = ot * 4;

    float acc[4][4];
    {
        float4 b4 = *(const float4*)(bias + o0);
        float bb[4] = {b4.x, b4.y, b4.z, b4.w};
#pragma unroll
        for (int oo = 0; oo < 4; ++oo)
#pragma unroll
            for (int ww = 0; ww < 4; ++ww) acc[oo][ww] = bb[oo];
    }

    for (int ck = 0; ck < 4; ++ck) {
        __syncthreads();
        for (int idx = tid; idx < 3168; idx += 256) {
            int col = idx % 66;
            int row = idx / 66;
            int dy = row % 3, cil = row / 3;
            int ci = ck * 16 + cil;
            int hs = h + dy - 1;
            float val = 0.0f;
            if (col >= 1 && col <= 64 && hs >= 0 && hs < 64)
                val = x[((b * 64 + ci) * 64 + hs) * 64 + (col - 1)];
            xch[(cil * 3 + dy) * 66 + col] = val;
        }
        for (int idx = tid; idx < 2304; idx += 256)
            ((float4*)wch)[idx] = ((const float4*)(wtc + ck * 9216))[idx];
        __syncthreads();

        for (int cil = 0; cil < 16; ++cil) {
#pragma unroll
            for (int dy = 0; dy < 3; ++dy) {
                float xv[6];
#pragma unroll
                for (int s = 0; s < 6; ++s) xv[s] = xch[(cil * 3 + dy) * 66 + w0 + s];
#pragma unroll
                for (int dx = 0; dx < 3; ++dx) {
                    float4 w4 = ((const float4*)wch)[(cil * 9 + dy * 3 + dx) * 16 + ot];
                    float wa[4] = {w4.x, w4.y, w4.z, w4.w};
#pragma unroll
                    for (int oo = 0; oo < 4; ++oo)
#pragma unroll
                        for (int ww = 0; ww < 4; ++ww)
                            acc[oo][ww] += xv[ww + dx] * wa[oo];
                }
            }
        }
    }

    if (conv < 2) {
        unsigned short* oh = (conv == 0) ? qth : kth;
        unsigned short* ol = (conv == 0) ? qtl : ktl;
#pragma unroll
        for (int ww = 0; ww < 4; ++ww) {
            unsigned short h4[4], l4[4];
#pragma unroll
            for (int oo = 0; oo < 4; ++oo) split2(acc[oo][ww], h4[oo], l4[oo]);
            int ad = (b * 4096 + h * 64 + w0 + ww) * 64 + o0;
            uint2 hv, lv;
            hv.x = h4[0] | ((unsigned int)h4[1] << 16);
            hv.y = h4[2] | ((unsigned int)h4[3] << 16);
            lv.x = l4[0] | ((unsigned int)l4[1] << 16);
            lv.y = l4[2] | ((unsigned int)l4[3] << 16);
            *(uint2*)(oh + ad) = hv;
            *(uint2*)(ol + ad) = lv;
        }
    } else {
        int cb = o0 >> 4, ccb = o0 & 15;
#pragma unroll
        for (int ww = 0; ww < 4; ++ww) {
            int n = h * 64 + w0 + ww;
            int n8 = n >> 3, e = n & 7;
            int basead = ((b * 4 + cb) * 512 + n8) * 16;
#pragma unroll
            for (int oo = 0; oo < 4; ++oo) {
                unsigned short hh, ll;
                split2(acc[oo][ww], hh, ll);
                vbh[(basead + ccb + oo) * 8 + e] = hh;
                vbl[(basead + ccb + oo) * 8 + e] = ll;
            }
        }
    }
}

// ---------------- channel Gram partials (unchanged)
__global__ __launch_bounds__(256) void k_gram(const float* __restrict__ x, float* __restrict__ Gpart) {
    int nc = blockIdx.x, b = blockIdx.y;
    __shared__ float xs[64 * 257];
    int tid = threadIdx.x;
    for (int it = 0; it < 16; ++it) {
        int f4i = tid + it * 256;
        int c = f4i >> 6, n4 = f4i & 63;
        float4 vv = *(const float4*)(x + (b * 64 + c) * 4096 + nc * 256 + n4 * 4);
        xs[c * 257 + n4 * 4 + 0] = vv.x;
        xs[c * 257 + n4 * 4 + 1] = vv.y;
        xs[c * 257 + n4 * 4 + 2] = vv.z;
        xs[c * 257 + n4 * 4 + 3] = vv.w;
    }
    __syncthreads();
    int tc = tid & 15, td = tid >> 4;
    int c0 = tc * 4, d0 = td * 4;
    float acc[4][4];
#pragma unroll
    for (int i = 0; i < 4; ++i)
#pragma unroll
        for (int j = 0; j < 4; ++j) acc[i][j] = 0.0f;
    for (int n = 0; n < 256; ++n) {
        float xc[4], xd[4];
#pragma unroll
        for (int i = 0; i < 4; ++i) xc[i] = xs[(c0 + i) * 257 + n];
#pragma unroll
        for (int j = 0; j < 4; ++j) xd[j] = xs[(d0 + j) * 257 + n];
#pragma unroll
        for (int i = 0; i < 4; ++i)
#pragma unroll
            for (int j = 0; j < 4; ++j) acc[i][j] += xc[i] * xd[j];
    }
#pragma unroll
    for (int i = 0; i < 4; ++i) {
        float4 o4 = {acc[i][0], acc[i][1], acc[i][2], acc[i][3]};
        *(float4*)(Gpart + ((nc * 4 + b) * 64 + c0 + i) * 64 + d0) = o4;
    }
}

// ---------------- channel softmax rows (unchanged)
__global__ void k_asm(const float* __restrict__ Gpart, float* __restrict__ A) {
    int row = blockIdx.x;      // b*64 + c
    int d = threadIdx.x;
    int b = row >> 6, c = row & 63;
    float g = 0.0f;
    for (int p = 0; p < 16; ++p) g += Gpart[(p * 4 + b) * 4096 + c * 64 + d];
    float mx = g;
    for (int off = 32; off >= 1; off >>= 1) mx = fmaxf(mx, __shfl_xor(mx, off, 64));
    float e = __expf(g - mx);
    float s = e;
    for (int off = 32; off >= 1; off >>= 1) s += __shfl_xor(s, off, 64);
    A[row * 64 + d] = e / s;
}

// ---------------- pass1: row sums l_i = sum_j exp(s_ij).
// grid 512; block 256 (4 waves). Wave = 64 i-rows (4 Q-frag sets) -> each K
// fragment feeds 4 MFMA chains. K tiles (64 j) staged in LDS once per block.
__global__ __launch_bounds__(256, 2) void k_pass1(
        const unsigned short* __restrict__ qth, const unsigned short* __restrict__ qtl,
        const unsigned short* __restrict__ kth, const unsigned short* __restrict__ ktl,
        float* __restrict__ lpart) {
    int flat = blockIdx.x;
    int xcd = flat & 7, slot = flat >> 3;        // slot 0..63
    int b = xcd >> 1;
    int rem = (xcd & 1) * 64 + slot;             // 0..127
    int itile = rem & 15, jp = rem >> 4;         // itile 0..15, jp 0..7

    __shared__ unsigned short ksh[64 * 72];      // stride 72 shorts (144B == 16 mod 128)
    __shared__ unsigned short ksl[64 * 72];

    int tid = threadIdx.x;
    int lane = tid & 63, wv = tid >> 6;
    int l15 = lane & 15, g = lane >> 4;
    int iw = itile * 256 + wv * 64;              // wave strip base (64 rows)

    s8v qa[4][4];                                // [sub-strip][h0,l0,h1,l1]
#pragma unroll
    for (int ss = 0; ss < 4; ++ss) {
        int qb = (b * 4096 + iw + ss * 16 + l15) * 64 + g * 8;
        qa[ss][0] = *(const s8v*)(qth + qb);
        qa[ss][1] = *(const s8v*)(qtl + qb);
        qa[ss][2] = *(const s8v*)(qth + qb + 32);
        qa[ss][3] = *(const s8v*)(qtl + qb + 32);
    }

    float l[4][4];
#pragma unroll
    for (int ss = 0; ss < 4; ++ss)
#pragma unroll
        for (int r = 0; r < 4; ++r) l[ss][r] = 0.f;

    for (int jt = 0; jt < 8; ++jt) {
        int j0 = jp * 512 + jt * 64;
        __syncthreads();
#pragma unroll
        for (int itr = 0; itr < 2; ++itr) {      // 512 16B-segs, 2 per thread
            int s = tid + itr * 256;
            int row = s >> 3, c16 = s & 7;
            int gsrc = (b * 4096 + j0 + row) * 64 + c16 * 8;
            *(s8v*)(ksh + row * 72 + c16 * 8) = *(const s8v*)(kth + gsrc);
            *(s8v*)(ksl + row * 72 + c16 * 8) = *(const s8v*)(ktl + gsrc);
        }
        __syncthreads();
#pragma unroll
        for (int js = 0; js < 4; ++js) {
            int ro = (js * 16 + l15) * 72 + g * 8;
            s8v bh0 = *(const s8v*)(ksh + ro);
            s8v bl0 = *(const s8v*)(ksl + ro);
            s8v bh1 = *(const s8v*)(ksh + ro + 32);
            s8v bl1 = *(const s8v*)(ksl + ro + 32);
#pragma unroll
            for (int ss = 0; ss < 4; ++ss) {
                f4v acc = {0.f, 0.f, 0.f, 0.f};
                acc = MFMA16(qa[ss][0], bh0, acc);
                acc = MFMA16(qa[ss][0], bl0, acc);
                acc = MFMA16(qa[ss][1], bh0, acc);
                acc = MFMA16(qa[ss][2], bh1, acc);
                acc = MFMA16(qa[ss][2], bl1, acc);
                acc = MFMA16(qa[ss][3], bh1, acc);
                l[ss][0] += __expf(acc[0]);
                l[ss][1] += __expf(acc[1]);
                l[ss][2] += __expf(acc[2]);
                l[ss][3] += __expf(acc[3]);
            }
        }
    }
#pragma unroll
    for (int ss = 0; ss < 4; ++ss)
#pragma unroll
        for (int r = 0; r < 4; ++r) {
            float s = l[ss][r];
            s += __shfl_xor(s, 1);
            s += __shfl_xor(s, 2);
            s += __shfl_xor(s, 4);
            s += __shfl_xor(s, 8);
            l[ss][r] = s;
        }
    if (l15 == 0) {
        int ib = (jp * 4 + b) * 4096 + iw + g * 4;
#pragma unroll
        for (int ss = 0; ss < 4; ++ss)
#pragma unroll
            for (int r = 0; r < 4; ++r)
                lpart[ib + ss * 16 + r] = l[ss][r];
    }
}

// ---------------- merge 8 j-partials -> 1/l
__global__ void k_merge(const float* __restrict__ lpart, float* __restrict__ invl) {
    int idx = blockIdx.x * 256 + threadIdx.x;
    float s = 0.0f;
#pragma unroll
    for (int p = 0; p < 8; ++p) s += lpart[p * 16384 + idx];
    invl[idx] = 1.0f / s;
}

// ---------------- pass2: grid 256, block 512 (8 waves), j-tile 64.
// K (64 j) in registers; V double-buffered via global_load_lds (linear layout);
// P hi-only bf16 in LDS, transposed [j][i] (fragment-ready for PV B-operand).
__global__ __launch_bounds__(512, 2) void k_pass2(
        const unsigned short* __restrict__ qth, const unsigned short* __restrict__ qtl,
        const unsigned short* __restrict__ kth, const unsigned short* __restrict__ ktl,
        const unsigned short* __restrict__ vbh, const unsigned short* __restrict__ vbl,
        const float* __restrict__ invl, float* __restrict__ pos) {
    int flat = blockIdx.x;                      // 0..255
    int xcd = flat & 7;
    int b = xcd >> 1;
    int jt = (xcd & 1) * 32 + (flat >> 3);      // 0..63
    int j0 = jt * 64;

    int tid = threadIdx.x;
    int lane = tid & 63, wv = tid >> 6;
    int l15 = lane & 15, g = lane >> 4;

    __shared__ unsigned short Pt[64][136];       // [j][i 0..127], stride 272B
    __shared__ unsigned short Vt[2][2][4][2048]; // [buf][hl][cb][n8' 16][cc 16][e 8]

    s8v kf[4][4];                                // [js][{h0,l0,h1,l1}]
#pragma unroll
    for (int js = 0; js < 4; ++js) {
        int kb = (b * 4096 + j0 + js * 16 + l15) * 64 + g * 8;
        kf[js][0] = *(const s8v*)(kth + kb);
        kf[js][1] = *(const s8v*)(ktl + kb);
        kf[js][2] = *(const s8v*)(kth + kb + 32);
        kf[js][3] = *(const s8v*)(ktl + kb + 32);
    }

    int cq = wv & 3, jh = wv >> 2;
    f4v acc0a = {0,0,0,0}, acc0b = {0,0,0,0};    // jsub 0, ic {0,1} / {2,3}
    f4v acc1a = {0,0,0,0}, acc1b = {0,0,0,0};    // jsub 1

    // stage V i-chunk (128 rows) for iteration `it` into Vt[buf].
    // wave wv stages slice (hl = wv>>2, cb = wv&3): 4KB contiguous.
    auto stageV = [&](int buf, int it) {
        const unsigned short* src = (wv < 4) ? vbh : vbl;
        int cb = wv & 3;
        const unsigned short* sp = src + (((b * 4 + cb) * 512 + it * 16) * 128);
        unsigned short* dp = &Vt[buf][wv >> 2][cb][0];
#pragma unroll
        for (int u = 0; u < 4; ++u)
            gl_lds16(sp + u * 512 + lane * 8, dp + u * 512);
    };

    stageV(0, 0);
    for (int it = 0; it < 32; ++it) {
        int buf = it & 1;
        __syncthreads();                 // prev PV done reading Pt and Vt[buf^1]
        if (it < 31) stageV(buf ^ 1, it + 1);

        // ---- QK phase: wave = 16-row i-strip
        int iw = it * 128 + wv * 16;
        int qb = (b * 4096 + iw + l15) * 64 + g * 8;
        s8v qa0 = *(const s8v*)(qth + qb);
        s8v ql0 = *(const s8v*)(qtl + qb);
        s8v qa1 = *(const s8v*)(qth + qb + 32);
        s8v ql1 = *(const s8v*)(qtl + qb + 32);
        float4 v4 = *(const float4*)(invl + b * 4096 + iw + g * 4);
        float ivr[4] = {v4.x, v4.y, v4.z, v4.w};

#pragma unroll
        for (int js = 0; js < 4; ++js) {
            f4v acc = {0,0,0,0};
            acc = MFMA16(qa0, kf[js][0], acc);
            acc = MFMA16(qa0, kf[js][1], acc);
            acc = MFMA16(ql0, kf[js][0], acc);
            acc = MFMA16(qa1, kf[js][2], acc);
            acc = MFMA16(qa1, kf[js][3], acc);
            acc = MFMA16(ql1, kf[js][2], acc);
            // lane holds S rows i = iw + g*4 + r, col j = js*16 + l15
            unsigned short pw[4];
#pragma unroll
            for (int r = 0; r < 4; ++r) pw[r] = bf16_rne(__expf(acc[r]) * ivr[r]);
            uint2 pk;
            pk.x = pw[0] | ((unsigned int)pw[1] << 16);
            pk.y = pw[2] | ((unsigned int)pw[3] << 16);
            *(uint2*)&Pt[js * 16 + l15][wv * 16 + g * 4] = pk;
        }
        __syncthreads();                 // Pt ready; Vt[buf] drained (vmcnt at barrier)

        // ---- PV phase: wave = (cq 16 c) x (jh 32 j)
#pragma unroll
        for (int ic = 0; ic < 4; ++ic) {
            int va = ((ic * 4 + g) * 16 + l15) * 8;
            s8v ah = *(const s8v*)&Vt[buf][0][cq][va];
            s8v al = *(const s8v*)&Vt[buf][1][cq][va];
            s8v p0 = *(const s8v*)&Pt[jh * 32 + l15][ic * 32 + g * 8];
            s8v p1 = *(const s8v*)&Pt[jh * 32 + 16 + l15][ic * 32 + g * 8];
            if (ic < 2) {
                acc0a = MFMA16(ah, p0, acc0a);
                acc0a = MFMA16(al, p0, acc0a);
                acc1a = MFMA16(ah, p1, acc1a);
                acc1a = MFMA16(al, p1, acc1a);
            } else {
                acc0b = MFMA16(ah, p0, acc0b);
                acc0b = MFMA16(al, p0, acc0b);
                acc1b = MFMA16(ah, p1, acc1b);
                acc1b = MFMA16(al, p1, acc1b);
            }
        }
    }

    f4v o0 = acc0a + acc0b;
    f4v o1 = acc1a + acc1b;
    int cb2 = b * 64 + cq * 16 + g * 4;
    int jb = j0 + jh * 32 + l15;
#pragma unroll
    for (int r = 0; r < 4; ++r) {
        pos[(cb2 + r) * 4096 + jb] = o0[r];
        pos[(cb2 + r) * 4096 + jb + 16] = o1[r];
    }
}

// ---------------- final: out = pg*pos + cg*(A@x) + 2*x, LDS-staged x tile
__global__ __launch_bounds__(256) void k_final(
        const float* __restrict__ x, const float* __restrict__ pos,
        const float* __restrict__ A, const float* __restrict__ pg,
        const float* __restrict__ cg, float* __restrict__ out) {
    int n0 = blockIdx.x * 256, cg8 = blockIdx.y, b = blockIdx.z;
    __shared__ float xs[64 * 256];
    int tid = threadIdx.x;
    for (int it = 0; it < 16; ++it) {
        int idx = tid + it * 256;           // float4 index
        int d = idx >> 6, n4 = idx & 63;
        *(float4*)(xs + d * 256 + n4 * 4) =
            *(const float4*)(x + (b * 64 + d) * 4096 + n0 + n4 * 4);
    }
    __syncthreads();
    float pgv = pg[0], cgv = cg[0];
    int cbase = cg8 * 8;
#pragma unroll
    for (int c8 = 0; c8 < 8; ++c8) {
        int c = cbase + c8;
        const float* Ar = A + (b * 64 + c) * 64;
        float acc = 0.0f;
#pragma unroll
        for (int d = 0; d < 64; ++d) acc += Ar[d] * xs[d * 256 + tid];
        float xc = xs[c * 256 + tid];
        float p = pos[(b * 64 + c) * 4096 + n0 + tid];
        out[(b * 64 + c) * 4096 + n0 + tid] = pgv * p + cgv * acc + 2.0f * xc;
    }
}

extern "C" void kernel_launch(void* const* d_in, const int* in_sizes, int n_in,
                              void* d_out, int out_size, void* d_ws, size_t ws_size,
                              hipStream_t stream) {
    const float* x  = (const float*)d_in[0];
    const float* wq = (const float*)d_in[1];
    const float* bq = (const float*)d_in[2];
    const float* wk = (const float*)d_in[3];
    const float* bk = (const float*)d_in[4];
    const float* wv = (const float*)d_in[5];
    const float* bv = (const float*)d_in[6];
    const float* pg = (const float*)d_in[7];
    const float* cg = (const float*)d_in[8];
    float* out = (float*)d_out;

    if (ws_size < (size_t)WS_FLOATS * sizeof(float)) return;
    float* ws = (float*)d_ws;
    float* pos  = ws + OFF_POS;
    unsigned short* qth = (unsigned short*)(ws + OFF_QTH);
    unsigned short* qtl = (unsigned short*)(ws + OFF_QTL);
    unsigned short* kth = (unsigned short*)(ws + OFF_KTH);
    unsigned short* ktl = (unsigned short*)(ws + OFF_KTL);
    unsigned short* vbh = (unsigned short*)(ws + OFF_VBH);
    unsigned short* vbl = (unsigned short*)(ws + OFF_VBL);
    float* wt   = ws + OFF_WT;
    float* lp   = ws + OFF_LPART;
    float* invl = ws + OFF_INVL;
    float* Gp   = ws + OFF_GPART;
    float* A    = ws + OFF_A;

    k_wtrans<<<432, 256, 0, stream>>>(wq, wk, wv, wt);
    k_conv<<<dim3(64, 4, 3), 256, 0, stream>>>(x, wt, bq, bk, bv, qth, qtl, kth, ktl, vbh, vbl);
    k_gram<<<dim3(16, 4), 256, 0, stream>>>(x, Gp);
    k_asm<<<256, 64, 0, stream>>>(Gp, A);
    k_pass1<<<512, 256, 0, stream>>>(qth, qtl, kth, ktl, lp);
    k_merge<<<64, 256, 0, stream>>>(lp, invl);
    k_pass2<<<256, 512, 0, stream>>>(qth, qtl, kth, ktl, vbh, vbl, invl, pos);
    k_final<<<dim3(16, 8, 4), 256, 0, stream>>>(x, pos, A, pg, cg, out);
}